// Round 8
// baseline (566.026 us; speedup 1.0000x reference)
//
#include <hip/hip_runtime.h>
#include <math.h>

#define HW 4096

typedef __attribute__((ext_vector_type(8))) short bh8;
typedef __attribute__((ext_vector_type(4))) float f32x4;
typedef unsigned int u32;
typedef unsigned short u16;

__device__ __forceinline__ u16 f2bf(float f) {
  union { float f; u32 u; } v; v.f = f;
  u32 u = v.u;
  return (u16)((u + 0x7FFFu + ((u >> 16) & 1u)) >> 16);
}
__device__ __forceinline__ float bf2f(u16 h) {
  union { u32 u; float f; } v; v.u = ((u32)h) << 16;
  return v.f;
}

// ---------------------------------------------------------------------------
// kv projection (+ fused conv-weight convert prologue).
// Branch 1 (spatial attn): K1 -> bf16 n-major (b,4096,64), V1 -> bf16
// ch-major (b,64,4096). Branch 2 (channel attn): fp32 ch-major.
// grid (64 nblk, 8 b), block 256
// ---------------------------------------------------------------------------
__global__ __launch_bounds__(256) void kv_proj(
    const float* __restrict__ xs,
    const float* __restrict__ w1, const float* __restrict__ b1,
    const float* __restrict__ w2, const float* __restrict__ b2,
    u32* __restrict__ Knm, u16* __restrict__ Vcm,
    float* __restrict__ K2t, float* __restrict__ V2t,
    const float* __restrict__ cw, const float* __restrict__ gamma,
    const float* __restrict__ beta, const float* __restrict__ mean,
    const float* __restrict__ var, u16* __restrict__ Wg,
    float* __restrict__ shb) {
  __shared__ float Ss[64][65];
  __shared__ float Ws[128 * 64];
  __shared__ u32 LtK[64][33];  // packed bf16x2 K rows, conflict-free pitch
  const int b = blockIdx.y, n0 = blockIdx.x * 64;
  const int t = threadIdx.x;
  const int lane_n = t & 63, jg = t >> 6;
  const int jbase = jg * 32;
  const float* xsb = xs + (size_t)b * 128 * HW;

  // ---- fused wcvt: conv_w (oc,ic,3,3) -> Wg[tap][oc][ic] bf16, BN folded ----
  {
    int gid = (blockIdx.y * 64 + blockIdx.x) * 256 + t;  // 0..131071
    for (int i = gid; i < 147456; i += 131072) {
      int tap = i >> 14, oc = (i >> 7) & 127, ic = i & 127;
      float sc = gamma[oc] * rsqrtf(var[oc] + 1e-5f);
      Wg[i] = f2bf(cw[((size_t)(oc * 128 + ic)) * 9 + tap] * sc);
    }
    if (gid < 128) {
      float sc = gamma[gid] * rsqrtf(var[gid] + 1e-5f);
      shb[gid] = beta[gid] - mean[gid] * sc;
    }
  }

  for (int br = 0; br < 2; ++br) {
    const float* W = br ? w2 : w1;
    const float* bias = br ? b2 : b1;
    const float* src = xsb + (br ? 64 * HW : 0);
    __syncthreads();
    for (int s = 0; s < 16; ++s) {
      int ch = s * 4 + jg;
      Ss[ch][lane_n] = src[(size_t)ch * HW + n0 + lane_n];
    }
    for (int i = t; i < 128 * 64; i += 256) Ws[i] = W[i];
    __syncthreads();

    float acc[32];
#pragma unroll
    for (int i = 0; i < 32; ++i) acc[i] = bias[jbase + i];
    for (int ch = 0; ch < 64; ++ch) {
      float s = Ss[ch][lane_n];
#pragma unroll
      for (int i = 0; i < 32; ++i) acc[i] = fmaf(Ws[(jbase + i) * 64 + ch], s, acc[i]);
    }

    if (br == 0) {
      if (jg < 2) {  // K channels jbase..jbase+31 -> pack to LDS
#pragma unroll
        for (int i2 = 0; i2 < 16; ++i2) {
          u32 p = (u32)f2bf(acc[2 * i2]) | ((u32)f2bf(acc[2 * i2 + 1]) << 16);
          LtK[lane_n][jg * 16 + i2] = p;
        }
      } else {  // V channels (jbase-64)..+31 -> bf16 ch-major global
#pragma unroll
        for (int i = 0; i < 32; ++i) {
          int ch = jbase - 64 + i;
          Vcm[((size_t)b * 64 + ch) * HW + n0 + lane_n] = f2bf(acc[i]);
        }
      }
      __syncthreads();
      // coalesced n-major K write: rows of 32 uints (64 bf16)
#pragma unroll
      for (int p = 0; p < 8; ++p) {
        int idx = p * 256 + t;
        int n = idx >> 5, cc = idx & 31;
        Knm[((size_t)b * HW + n0 + n) * 32 + cc] = LtK[n][cc];
      }
    } else {
      float* Kt = K2t + (size_t)b * 64 * HW;
      float* Vt = V2t + (size_t)b * 64 * HW;
#pragma unroll
      for (int i = 0; i < 32; ++i) {
        int j = jbase + i;
        float* dst = (j < 64) ? (Kt + (size_t)j * HW) : (Vt + (size_t)(j - 64) * HW);
        dst[n0 + lane_n] = acc[i];
      }
    }
  }
}

// ---------------------------------------------------------------------------
// MFMA flash attention, key-split partials. grid (64 qblk, 8 b, 2 khalf),
// block 256 (4 waves). Each block processes 16 of 32 key-tiles with the
// round-6 barrier-free inner loop (single wave-private P, f2bf pack),
// writes unnormalized partial O (bf16 n-major) + partial l (fp32).
// 1024 blocks -> 4 blocks/CU -> 4 waves/SIMD.
// ---------------------------------------------------------------------------
__device__ __forceinline__ void attn_step(
    const bh8* kf, const bh8* vf, const bh8 (&qb)[4][2],
    f32x4 (&O)[4][4], float (&lsum)[4], u16* Pw, int lq, int quad) {
  f32x4 S[2][4];
#pragma unroll
  for (int mt = 0; mt < 2; ++mt)
#pragma unroll
    for (int nt = 0; nt < 4; ++nt) {
      f32x4 a = (f32x4)(0.f);
      a = __builtin_amdgcn_mfma_f32_16x16x32_bf16(kf[mt * 2 + 0], qb[nt][0], a, 0, 0, 0);
      a = __builtin_amdgcn_mfma_f32_16x16x32_bf16(kf[mt * 2 + 1], qb[nt][1], a, 0, 0, 0);
      S[mt][nt] = a;
    }
#pragma unroll
  for (int mt = 0; mt < 2; ++mt)
#pragma unroll
    for (int nt = 0; nt < 4; ++nt) {
      float p0 = __expf(S[mt][nt][0] - 12.f);
      float p1 = __expf(S[mt][nt][1] - 12.f);
      float p2 = __expf(S[mt][nt][2] - 12.f);
      float p3 = __expf(S[mt][nt][3] - 12.f);
      lsum[nt] += (p0 + p1) + (p2 + p3);
      u32 lo = (u32)f2bf(p0) | ((u32)f2bf(p1) << 16);
      u32 hi = (u32)f2bf(p2) | ((u32)f2bf(p3) << 16);
      *(uint2*)&Pw[(nt * 16 + lq) * 36 + mt * 16 + quad * 4] = make_uint2(lo, hi);
    }
#pragma unroll
  for (int nt = 0; nt < 4; ++nt) {
    bh8 pb = *(const bh8*)&Pw[(nt * 16 + lq) * 36 + quad * 8];
#pragma unroll
    for (int ct = 0; ct < 4; ++ct)
      O[ct][nt] = __builtin_amdgcn_mfma_f32_16x16x32_bf16(vf[ct], pb, O[ct][nt], 0, 0, 0);
  }
}

#define LOADKV(KB, KF, VF)                                            \
  do {                                                                \
    const int n0_ = (KB) * 128;                                       \
    const u16* kr_ = Kb + (size_t)(n0_ + wb + lq) * 64 + quad * 8;    \
    KF[0] = *(const bh8*)(kr_);                                       \
    KF[1] = *(const bh8*)(kr_ + 32);                                  \
    KF[2] = *(const bh8*)(kr_ + 1024);                                \
    KF[3] = *(const bh8*)(kr_ + 1056);                                \
    const u16* vr_ = Vb + (size_t)lq * HW + n0_ + wb + quad * 8;      \
    VF[0] = *(const bh8*)(vr_);                                       \
    VF[1] = *(const bh8*)(vr_ + 16 * HW);                             \
    VF[2] = *(const bh8*)(vr_ + 32 * HW);                             \
    VF[3] = *(const bh8*)(vr_ + 48 * HW);                             \
  } while (0)

__global__ __launch_bounds__(256, 4) void attn_mfma(
    const float* __restrict__ xu,
    const u16* __restrict__ Knm, const u16* __restrict__ Vcm,
    u16* __restrict__ Oph, float* __restrict__ Lp) {
  __shared__ __align__(16) u16 SMEM[18432];  // 36864 B
  const int b = blockIdx.y, q0 = blockIdx.x * 64;
  const int half = blockIdx.z;
  const int t = threadIdx.x;
  const int wq = t >> 6, lane = t & 63, lq = lane & 15, quad = lane >> 4;
  const int wb = wq * 32;  // wave's key-slice base within a 128-key tile
  const float* xub = xu + (size_t)b * 128 * HW;
  const u16* Kb = Knm + (size_t)b * HW * 64;
  const u16* Vb = Vcm + (size_t)b * 64 * HW;
  u16* Pw = SMEM + wq * 64 * 36;  // wave-private P (q,k) tile

  // Q B-fragments: all 64 q x 64 ch per wave (B[n=q][k=ch])
  bh8 qb[4][2];
#pragma unroll
  for (int nt = 0; nt < 4; ++nt)
#pragma unroll
    for (int s = 0; s < 2; ++s)
#pragma unroll
      for (int j = 0; j < 8; ++j) {
        int ch = s * 32 + quad * 8 + j;
        qb[nt][s][j] = (short)f2bf(xub[(size_t)ch * HW + q0 + nt * 16 + lq]);
      }

  f32x4 O[4][4];  // [ct: ch-tile][nt: q-tile], C: row=ch_local, col=q_local
#pragma unroll
  for (int ct = 0; ct < 4; ++ct)
#pragma unroll
    for (int nt = 0; nt < 4; ++nt) O[ct][nt] = (f32x4)(0.f);
  float lsum[4] = {0.f, 0.f, 0.f, 0.f};

  const int k0 = half * 16, k1 = k0 + 16;
  bh8 kfa[4], vfa[4], kfb[4], vfb[4];
  LOADKV(k0, kfa, vfa);
  for (int kb = k0; kb < k1; kb += 2) {
    LOADKV(kb + 1, kfb, vfb);
    attn_step(kfa, vfa, qb, O, lsum, Pw, lq, quad);
    if (kb + 2 < k1) LOADKV(kb + 2, kfa, vfa);
    attn_step(kfb, vfb, qb, O, lsum, Pw, lq, quad);
  }

  // ---- epilogue: cross-wave reduce, write bf16 partial O + fp32 partial l ----
#pragma unroll
  for (int nt = 0; nt < 4; ++nt) {
    lsum[nt] += __shfl_xor(lsum[nt], 16);
    lsum[nt] += __shfl_xor(lsum[nt], 32);
  }
  __syncthreads();  // all waves done with their Pw before SMEM reuse
  float* Posc = (float*)SMEM;            // [4 waves][32 ch][68 q] = 34816 B
  float* Lred = (float*)(SMEM + 17408);  // [4 waves][64 q] = 1024 B
  if (quad == 0) {
#pragma unroll
    for (int nt = 0; nt < 4; ++nt) Lred[(wq * 4 + nt) * 16 + lq] = lsum[nt];
  }

  const int q = t & 63, cg = t >> 6;
  u16* orow = Oph + (((size_t)(half * 8 + b) * HW) + q0 + q) * 64;
#pragma unroll
  for (int rh = 0; rh < 2; ++rh) {
    if (rh) __syncthreads();  // previous half's readers done
#pragma unroll
    for (int c2 = 0; c2 < 2; ++c2)
#pragma unroll
      for (int nt = 0; nt < 4; ++nt)
#pragma unroll
        for (int r = 0; r < 4; ++r)
          Posc[(wq * 32 + c2 * 16 + quad * 4 + r) * 68 + nt * 16 + lq] =
              O[rh * 2 + c2][nt][r];
    __syncthreads();
    u16 h[8];
#pragma unroll
    for (int i = 0; i < 8; ++i) {
      int chl = cg * 8 + i;
      float s = 0.f;
#pragma unroll
      for (int w2 = 0; w2 < 4; ++w2) s += Posc[(w2 * 32 + chl) * 68 + q];
      h[i] = f2bf(s);
    }
    u32 pk[4];
#pragma unroll
    for (int j = 0; j < 4; ++j) pk[j] = (u32)h[2 * j] | ((u32)h[2 * j + 1] << 16);
    *(uint4*)(orow + rh * 32 + cg * 8) = make_uint4(pk[0], pk[1], pk[2], pk[3]);
    if (rh == 0 && cg == 0) {
      float li = Lred[q] + Lred[64 + q] + Lred[128 + q] + Lred[192 + q];
      Lp[(size_t)(half * 8 + b) * HW + q0 + q] = li;
    }
  }
}

// ---------------------------------------------------------------------------
// Combine the two key-half partials: O=(O0+O1)/(l0+l1) + shortcut1, write
// xcat bf16 n-major ch 0..63. grid (64 qblk, 8 b), block 256.
// ---------------------------------------------------------------------------
__global__ __launch_bounds__(256) void attn_comb(
    const u16* __restrict__ Oph, const float* __restrict__ Lp,
    const float* __restrict__ xu, const float* __restrict__ xs,
    u16* __restrict__ xcat) {
  const int b = blockIdx.y, q0 = blockIdx.x * 64;
  const int t = threadIdx.x, q = t & 63, cg = t >> 6;
  const float* xub = xu + (size_t)b * 128 * HW;
  const float* xsb = xs + (size_t)b * 128 * HW;
  const size_t row = (size_t)b * HW + q0 + q;
  float inv = 1.f / (Lp[row] + Lp[(size_t)8 * HW + row]);
  const u16* p0 = Oph + row * 64;
  const u16* p1 = Oph + ((size_t)8 * HW * 64) + row * 64;
#pragma unroll
  for (int rh = 0; rh < 2; ++rh) {
    int cb = rh * 32 + cg * 8;
    uint4 a = *(const uint4*)(p0 + cb);
    uint4 c = *(const uint4*)(p1 + cb);
    const u16* ah = (const u16*)&a;
    const u16* ch_ = (const u16*)&c;
    u16 h[8];
#pragma unroll
    for (int i = 0; i < 8; ++i) {
      int ch = cb + i;
      size_t g = (size_t)ch * HW + q0 + q;
      float s = (bf2f(ah[i]) + bf2f(ch_[i])) * inv + xub[g] + xsb[g];
      h[i] = f2bf(s);
    }
    u32 pk[4];
#pragma unroll
    for (int j = 0; j < 4; ++j) pk[j] = (u32)h[2 * j] | ((u32)h[2 * j + 1] << 16);
    *(uint4*)(xcat + row * 128 + cb) = make_uint4(pk[0], pk[1], pk[2], pk[3]);
  }
}

// ---------------------------------------------------------------------------
// Channel gram partials: Mp[chunk][b][c][d] = sum over 128 n of u2[c,n]k2[d,n]
// grid (32 nchunk, 8 b), block 256.
// ---------------------------------------------------------------------------
__global__ __launch_bounds__(256) void chan_gram(
    const float* __restrict__ xu, const float* __restrict__ K2t,
    float* __restrict__ Mp) {
  __shared__ float Us[64][65], Ksm[64][65];
  const int b = blockIdx.y, n0 = blockIdx.x * 128;
  const int t = threadIdx.x, c = t & 63, dg = t >> 6;
  const float* ub = xu + ((size_t)b * 128 + 64) * HW;
  const float* kb = K2t + (size_t)b * 64 * HW;
  float acc[16];
#pragma unroll
  for (int i = 0; i < 16; ++i) acc[i] = 0.f;
  for (int s = 0; s < 2; ++s) {
    int nn = n0 + s * 64;
    __syncthreads();
    for (int r = 0; r < 16; ++r) {
      int row = r * 4 + dg;
      Us[row][c] = ub[(size_t)row * HW + nn + c];
      Ksm[row][c] = kb[(size_t)row * HW + nn + c];
    }
    __syncthreads();
    for (int n = 0; n < 64; ++n) {
      float u = Us[c][n];
#pragma unroll
      for (int i = 0; i < 16; ++i) acc[i] = fmaf(Ksm[dg * 16 + i][n], u, acc[i]);
    }
  }
  float* dst = Mp + ((size_t)blockIdx.x * 8 + b) * 4096 + c * 64 + dg * 16;
#pragma unroll
  for (int i = 0; i < 16; ++i) dst[i] = acc[i];
}

// reduce 32 chunk-partials -> M. grid 128, block 256.
__global__ void chan_reduce(const float* __restrict__ Mp, float* __restrict__ M) {
  int idx = blockIdx.x * 256 + threadIdx.x;  // 32768 cells
  float s = 0.f;
  for (int ch = 0; ch < 32; ++ch) s += Mp[(size_t)ch * 32768 + idx];
  M[idx] = s;
}

// ---------------------------------------------------------------------------
// chan_apply with fused softmax: A = softmax_c(M[b]) computed in-block, then
// cout[n][d] = sum_c v2[n][c]*A[c][d]; + shortcut2; bf16 n-major store.
// grid (64 nblk, 8 b), block 256
// ---------------------------------------------------------------------------
__global__ __launch_bounds__(256) void chan_apply(
    const float* __restrict__ V2t, const float* __restrict__ M,
    const float* __restrict__ xu, const float* __restrict__ xs,
    u16* __restrict__ xcat) {
  __shared__ float Vsm[64][65];
  __shared__ float As[64][65];
  __shared__ float red1[4][64], red2[4][64];
  const int b = blockIdx.y, n0 = blockIdx.x * 64, t = threadIdx.x;
  const int lane = t & 63, dg = t >> 6;
  const float* Vb = V2t + (size_t)b * 64 * HW;
  for (int s = 0; s < 16; ++s) {
    int c = s * 4 + dg;
    Vsm[lane][c] = Vb[(size_t)c * HW + n0 + lane];
  }
  for (int idx = t; idx < 4096; idx += 256) As[idx >> 6][idx & 63] = M[b * 4096 + idx];
  __syncthreads();
  // softmax over c per d=lane; this thread owns c in [dg*16, dg*16+16)
  float mx = -1e30f;
#pragma unroll
  for (int i = 0; i < 16; ++i) mx = fmaxf(mx, As[dg * 16 + i][lane]);
  red1[dg][lane] = mx;
  __syncthreads();
  mx = fmaxf(fmaxf(red1[0][lane], red1[1][lane]), fmaxf(red1[2][lane], red1[3][lane]));
  float se = 0.f;
#pragma unroll
  for (int i = 0; i < 16; ++i) {
    float e = __expf(As[dg * 16 + i][lane] - mx);
    As[dg * 16 + i][lane] = e;  // own cells only
    se += e;
  }
  red2[dg][lane] = se;
  __syncthreads();

  float acc[16];
#pragma unroll
  for (int i = 0; i < 16; ++i) acc[i] = 0.f;
  for (int c = 0; c < 64; ++c) {
    float v = Vsm[lane][c];
#pragma unroll
    for (int i = 0; i < 16; ++i) acc[i] = fmaf(v, As[c][dg * 16 + i], acc[i]);
  }
  const float* xub = xu + ((size_t)b * 128 + 64) * HW;
  const float* xsb = xs + ((size_t)b * 128 + 64) * HW;
  const int n = n0 + lane;
  u16 hv[16];
#pragma unroll
  for (int i = 0; i < 16; ++i) {
    int d = dg * 16 + i;
    float sm = red2[0][d] + red2[1][d] + red2[2][d] + red2[3][d];
    hv[i] = f2bf(acc[i] / sm + xub[(size_t)d * HW + n] + xsb[(size_t)d * HW + n]);
  }
  u32 pk[8];
#pragma unroll
  for (int j = 0; j < 8; ++j) pk[j] = (u32)hv[2 * j] | ((u32)hv[2 * j + 1] << 16);
  u16* ob = xcat + ((size_t)b * HW + n) * 128 + 64 + dg * 16;
  *(uint4*)(ob) = make_uint4(pk[0], pk[1], pk[2], pk[3]);
  *(uint4*)(ob + 8) = make_uint4(pk[4], pk[5], pk[6], pk[7]);
}

// ---------------------------------------------------------------------------
// Implicit-GEMM 3x3 conv via bf16 MFMA + fused BN(folded) + ReLU.
// Block: 512 thr = 8 waves (2 waves/SIMD). Tile: 128 spatial x 128 oc.
// Wave wq: m-tiles {2*(wq>>1), 2*(wq>>1)+1} x oc-half (wq&1)*64 (4 nt).
// grid (32 hblk, 8 b)
// ---------------------------------------------------------------------------
__global__ __launch_bounds__(512) void conv_mfma(
    const u16* __restrict__ X, const u16* __restrict__ Wg,
    const float* __restrict__ shb, float* __restrict__ out) {
  __shared__ __align__(16) u16 In[4 * 66 * 136];
  __shared__ __align__(16) u16 Wt[2][128 * 136];
  const int b = blockIdx.y, h0 = blockIdx.x * 2;
  const int t = threadIdx.x;
  const int wq = t >> 6, lane = t & 63, lq = lane & 15, quad = lane >> 4;
  const int nb = (wq & 1) * 64;       // oc-half base
  const int mb = (wq >> 1) * 2;       // m-tile pair base
  const u16* Xb = X + (size_t)b * HW * 128;

  // zero w-halo cells (iw = 0 and 65 for each ih)
  if (t < 128) {
    int ih = t >> 5, iwsel = (t >> 4) & 1, ck = t & 15;
    int iw = iwsel ? 65 : 0;
    *(uint4*)&In[(ih * 66 + iw) * 136 + ck * 8] = make_uint4(0, 0, 0, 0);
  }
  // stage input rows (zero h-halo out of range); 512 threads
  for (int ih = 0; ih < 4; ++ih) {
    int h = h0 - 1 + ih;
    bool ok = (h >= 0 && h < 64);
    const u16* src = Xb + (size_t)h * 64 * 128;
#pragma unroll
    for (int p = 0; p < 2; ++p) {
      int idx = p * 512 + t;
      int row = idx >> 4, ck = idx & 15;
      uint4 d = make_uint4(0, 0, 0, 0);
      if (ok) d = *(const uint4*)(src + (size_t)row * 128 + ck * 8);
      *(uint4*)&In[(ih * 66 + 1 + row) * 136 + ck * 8] = d;
    }
  }
  // stage tap-0 weights into buffer 0 (2048 uint4 over 512 threads = 4 passes)
  {
    const u16* src = Wg;
#pragma unroll
    for (int p = 0; p < 4; ++p) {
      int idx = p * 512 + t;
      int oc = idx >> 4, ck = idx & 15;
      uint4 d = *(const uint4*)(src + oc * 128 + ck * 8);
      *(uint4*)&Wt[0][oc * 136 + ck * 8] = d;
    }
  }
  __syncthreads();

  f32x4 acc[2][4];
#pragma unroll
  for (int mt = 0; mt < 2; ++mt)
#pragma unroll
    for (int nt = 0; nt < 4; ++nt) acc[mt][nt] = (f32x4)(0.f);

  for (int tap = 0; tap < 9; ++tap) {
    const int cur = tap & 1;
    if (tap < 8) {  // prefetch next tap into the other buffer
      const u16* src = Wg + (size_t)(tap + 1) * 128 * 128;
#pragma unroll
      for (int p = 0; p < 4; ++p) {
        int idx = p * 512 + t;
        int oc = idx >> 4, ck = idx & 15;
        uint4 d = *(const uint4*)(src + oc * 128 + ck * 8);
        *(uint4*)&Wt[cur ^ 1][oc * 136 + ck * 8] = d;
      }
    }
    const int dh = tap / 3, dw = tap - 3 * dh;
    const u16* Wc = &Wt[cur][0];
#pragma unroll
    for (int c = 0; c < 4; ++c) {
      bh8 bf[4];
#pragma unroll
      for (int nt = 0; nt < 4; ++nt)
        bf[nt] = *(const bh8*)&Wc[(nb + nt * 16 + lq) * 136 + c * 32 + quad * 8];
#pragma unroll
      for (int mt = 0; mt < 2; ++mt) {
        int s = (mb + mt) * 16 + lq;
        int ih = (s >> 6) + dh, iw = (s & 63) + dw;
        bh8 af = *(const bh8*)&In[(ih * 66 + iw) * 136 + c * 32 + quad * 8];
#pragma unroll
        for (int nt = 0; nt < 4; ++nt)
          acc[mt][nt] = __builtin_amdgcn_mfma_f32_16x16x32_bf16(af, bf[nt], acc[mt][nt], 0, 0, 0);
      }
    }
    __syncthreads();
  }

  // epilogue: +bias, ReLU, dense float4 stores
  float shv[4];
#pragma unroll
  for (int nt = 0; nt < 4; ++nt) shv[nt] = shb[nb + nt * 16 + lq];
#pragma unroll
  for (int mt = 0; mt < 2; ++mt) {
    int mtile = mb + mt;
    int h = h0 + (mtile >> 2);
    int w0 = ((mtile & 3) * 16) + quad * 4;
#pragma unroll
    for (int nt = 0; nt < 4; ++nt) {
      int oc = nb + nt * 16 + lq;
      float4 v;
      v.x = fmaxf(acc[mt][nt][0] + shv[nt], 0.f);
      v.y = fmaxf(acc[mt][nt][1] + shv[nt], 0.f);
      v.z = fmaxf(acc[mt][nt][2] + shv[nt], 0.f);
      v.w = fmaxf(acc[mt][nt][3] + shv[nt], 0.f);
      *(float4*)&out[((size_t)b * 128 + oc) * HW + h * 64 + w0] = v;
    }
  }
}

// ---------------------------------------------------------------------------
extern "C" void kernel_launch(void* const* d_in, const int* in_sizes, int n_in,
                              void* d_out, int out_size, void* d_ws, size_t ws_size,
                              hipStream_t stream) {
  const float* x_up   = (const float*)d_in[0];
  const float* x_skip = (const float*)d_in[1];
  const float* kv1_w  = (const float*)d_in[2];
  const float* kv1_b  = (const float*)d_in[3];
  const float* kv2_w  = (const float*)d_in[4];
  const float* kv2_b  = (const float*)d_in[5];
  const float* conv_w = (const float*)d_in[6];
  const float* bn_g   = (const float*)d_in[7];
  const float* bn_b   = (const float*)d_in[8];
  const float* bn_m   = (const float*)d_in[9];
  const float* bn_v   = (const float*)d_in[10];
  float* out = (float*)d_out;

  char* ws = (char*)d_ws;
  const size_t XCATB_B = (size_t)8 * HW * 128 * 2;  // 8.39 MB bf16 n-major
  const size_t KV32_B  = (size_t)8 * 64 * HW * 4;   // 8.39 MB
  const size_t KV16_B  = (size_t)8 * 64 * HW * 2;   // 4.19 MB
  size_t off = 0;
  u16*   xcat = (u16*)(ws + off);   off += XCATB_B;
  float* K2t  = (float*)(ws + off); off += KV32_B;
  float* V2t  = (float*)(ws + off); off += KV32_B;
  u32*   Knm  = (u32*)(ws + off);   off += KV16_B;
  u16*   Vcm  = (u16*)(ws + off);   off += KV16_B;
  float* Mp   = (float*)(ws + off); off += (size_t)32 * 8 * 4096 * 4;
  float* M    = (float*)(ws + off); off += (size_t)8 * 4096 * 4;
  u16*   Wg   = (u16*)(ws + off);   off += (size_t)9 * 128 * 128 * 2;
  float* shb  = (float*)(ws + off); off += 512;
  u16*   Oph  = (u16*)(ws + off);   off += (size_t)2 * 8 * HW * 64 * 2;  // 8.39 MB
  float* Lp   = (float*)(ws + off); off += (size_t)2 * 8 * HW * 4;       // 0.26 MB

  kv_proj<<<dim3(64, 8), 256, 0, stream>>>(x_skip, kv1_w, kv1_b, kv2_w, kv2_b,
                                           Knm, Vcm, K2t, V2t,
                                           conv_w, bn_g, bn_b, bn_m, bn_v, Wg, shb);
  attn_mfma<<<dim3(64, 8, 2), 256, 0, stream>>>(x_up, (const u16*)Knm, Vcm, Oph, Lp);
  attn_comb<<<dim3(64, 8), 256, 0, stream>>>(Oph, Lp, x_up, x_skip, xcat);
  chan_gram<<<dim3(32, 8), 256, 0, stream>>>(x_up, K2t, Mp);
  chan_reduce<<<128, 256, 0, stream>>>(Mp, M);
  chan_apply<<<dim3(64, 8), 256, 0, stream>>>(V2t, M, x_up, x_skip, xcat);
  conv_mfma<<<dim3(32, 8), 512, 0, stream>>>(xcat, Wg, shb, out);
}

// Round 9
// 325.162 us; speedup vs baseline: 1.7408x; 1.7408x over previous
//
#include <hip/hip_runtime.h>
#include <math.h>

#define HW 4096

typedef __attribute__((ext_vector_type(8))) short bh8;
typedef __attribute__((ext_vector_type(4))) float f32x4;
typedef unsigned int u32;
typedef unsigned short u16;

__device__ __forceinline__ u16 f2bf(float f) {
  union { float f; u32 u; } v; v.f = f;
  u32 u = v.u;
  return (u16)((u + 0x7FFFu + ((u >> 16) & 1u)) >> 16);
}

// ---------------------------------------------------------------------------
// kv projection (+ fused conv-weight convert prologue).
// Branch 1 (spatial attn): K1 -> bf16 n-major (b,4096,64), V1 -> bf16
// ch-major (b,64,4096). Branch 2 (channel attn): fp32 ch-major.
// grid (64 nblk, 8 b), block 256
// ---------------------------------------------------------------------------
__global__ __launch_bounds__(256) void kv_proj(
    const float* __restrict__ xs,
    const float* __restrict__ w1, const float* __restrict__ b1,
    const float* __restrict__ w2, const float* __restrict__ b2,
    u32* __restrict__ Knm, u16* __restrict__ Vcm,
    float* __restrict__ K2t, float* __restrict__ V2t,
    const float* __restrict__ cw, const float* __restrict__ gamma,
    const float* __restrict__ beta, const float* __restrict__ mean,
    const float* __restrict__ var, u16* __restrict__ Wg,
    float* __restrict__ shb) {
  __shared__ float Ss[64][65];
  __shared__ float Ws[128 * 64];
  __shared__ u32 LtK[64][33];  // packed bf16x2 K rows, conflict-free pitch
  const int b = blockIdx.y, n0 = blockIdx.x * 64;
  const int t = threadIdx.x;
  const int lane_n = t & 63, jg = t >> 6;
  const int jbase = jg * 32;
  const float* xsb = xs + (size_t)b * 128 * HW;

  // ---- fused wcvt: conv_w (oc,ic,3,3) -> Wg[tap][oc][ic] bf16, BN folded ----
  {
    int gid = (blockIdx.y * 64 + blockIdx.x) * 256 + t;  // 0..131071
    for (int i = gid; i < 147456; i += 131072) {
      int tap = i >> 14, oc = (i >> 7) & 127, ic = i & 127;
      float sc = gamma[oc] * rsqrtf(var[oc] + 1e-5f);
      Wg[i] = f2bf(cw[((size_t)(oc * 128 + ic)) * 9 + tap] * sc);
    }
    if (gid < 128) {
      float sc = gamma[gid] * rsqrtf(var[gid] + 1e-5f);
      shb[gid] = beta[gid] - mean[gid] * sc;
    }
  }

  for (int br = 0; br < 2; ++br) {
    const float* W = br ? w2 : w1;
    const float* bias = br ? b2 : b1;
    const float* src = xsb + (br ? 64 * HW : 0);
    __syncthreads();
    for (int s = 0; s < 16; ++s) {
      int ch = s * 4 + jg;
      Ss[ch][lane_n] = src[(size_t)ch * HW + n0 + lane_n];
    }
    for (int i = t; i < 128 * 64; i += 256) Ws[i] = W[i];
    __syncthreads();

    float acc[32];
#pragma unroll
    for (int i = 0; i < 32; ++i) acc[i] = bias[jbase + i];
    for (int ch = 0; ch < 64; ++ch) {
      float s = Ss[ch][lane_n];
#pragma unroll
      for (int i = 0; i < 32; ++i) acc[i] = fmaf(Ws[(jbase + i) * 64 + ch], s, acc[i]);
    }

    if (br == 0) {
      if (jg < 2) {  // K channels jbase..jbase+31 -> pack to LDS
#pragma unroll
        for (int i2 = 0; i2 < 16; ++i2) {
          u32 p = (u32)f2bf(acc[2 * i2]) | ((u32)f2bf(acc[2 * i2 + 1]) << 16);
          LtK[lane_n][jg * 16 + i2] = p;
        }
      } else {  // V channels (jbase-64)..+31 -> bf16 ch-major global
#pragma unroll
        for (int i = 0; i < 32; ++i) {
          int ch = jbase - 64 + i;
          Vcm[((size_t)b * 64 + ch) * HW + n0 + lane_n] = f2bf(acc[i]);
        }
      }
      __syncthreads();
      // coalesced n-major K write: rows of 32 uints (64 bf16)
#pragma unroll
      for (int p = 0; p < 8; ++p) {
        int idx = p * 256 + t;
        int n = idx >> 5, cc = idx & 31;
        Knm[((size_t)b * HW + n0 + n) * 32 + cc] = LtK[n][cc];
      }
    } else {
      float* Kt = K2t + (size_t)b * 64 * HW;
      float* Vt = V2t + (size_t)b * 64 * HW;
#pragma unroll
      for (int i = 0; i < 32; ++i) {
        int j = jbase + i;
        float* dst = (j < 64) ? (Kt + (size_t)j * HW) : (Vt + (size_t)(j - 64) * HW);
        dst[n0 + lane_n] = acc[i];
      }
    }
  }
}

// ---------------------------------------------------------------------------
// MFMA flash attention, 32-query blocks for occupancy. grid (128 qblk, 8 b),
// block 256 (4 waves, each owns a 32-key slice of every 128-key tile).
// Round-6 barrier-free inner loop: direct global->VGPR K/V with 2-deep
// register dbuf, exp(S-12) (no max tracking), single wave-private P LDS
// roundtrip. ~140 regs/wave -> 3 waves/SIMD legal (launch_bounds(256,3)).
// Epilogue: cross-wave reduce + normalize + shortcut, bf16 n-major store.
// ---------------------------------------------------------------------------
__device__ __forceinline__ void attn_step(
    const bh8* kf, const bh8* vf, const bh8 (&qb)[2][2],
    f32x4 (&O)[4][2], float (&lsum)[2], u16* Pw, int lq, int quad) {
  f32x4 S[2][2];
#pragma unroll
  for (int mt = 0; mt < 2; ++mt)
#pragma unroll
    for (int nt = 0; nt < 2; ++nt) {
      f32x4 a = (f32x4)(0.f);
      a = __builtin_amdgcn_mfma_f32_16x16x32_bf16(kf[mt * 2 + 0], qb[nt][0], a, 0, 0, 0);
      a = __builtin_amdgcn_mfma_f32_16x16x32_bf16(kf[mt * 2 + 1], qb[nt][1], a, 0, 0, 0);
      S[mt][nt] = a;
    }
#pragma unroll
  for (int mt = 0; mt < 2; ++mt)
#pragma unroll
    for (int nt = 0; nt < 2; ++nt) {
      float p0 = __expf(S[mt][nt][0] - 12.f);
      float p1 = __expf(S[mt][nt][1] - 12.f);
      float p2 = __expf(S[mt][nt][2] - 12.f);
      float p3 = __expf(S[mt][nt][3] - 12.f);
      lsum[nt] += (p0 + p1) + (p2 + p3);
      u32 lo = (u32)f2bf(p0) | ((u32)f2bf(p1) << 16);
      u32 hi = (u32)f2bf(p2) | ((u32)f2bf(p3) << 16);
      *(uint2*)&Pw[(nt * 16 + lq) * 36 + mt * 16 + quad * 4] = make_uint2(lo, hi);
    }
#pragma unroll
  for (int nt = 0; nt < 2; ++nt) {
    bh8 pb = *(const bh8*)&Pw[(nt * 16 + lq) * 36 + quad * 8];
#pragma unroll
    for (int ct = 0; ct < 4; ++ct)
      O[ct][nt] = __builtin_amdgcn_mfma_f32_16x16x32_bf16(vf[ct], pb, O[ct][nt], 0, 0, 0);
  }
}

#define LOADKV(KB, KF, VF)                                            \
  do {                                                                \
    const int n0_ = (KB) * 128;                                       \
    const u16* kr_ = Kb + (size_t)(n0_ + wb + lq) * 64 + quad * 8;    \
    KF[0] = *(const bh8*)(kr_);                                       \
    KF[1] = *(const bh8*)(kr_ + 32);                                  \
    KF[2] = *(const bh8*)(kr_ + 1024);                                \
    KF[3] = *(const bh8*)(kr_ + 1056);                                \
    const u16* vr_ = Vb + (size_t)lq * HW + n0_ + wb + quad * 8;      \
    VF[0] = *(const bh8*)(vr_);                                       \
    VF[1] = *(const bh8*)(vr_ + 16 * HW);                             \
    VF[2] = *(const bh8*)(vr_ + 32 * HW);                             \
    VF[3] = *(const bh8*)(vr_ + 48 * HW);                             \
  } while (0)

__global__ __launch_bounds__(256, 3) void attn_mfma(
    const float* __restrict__ xu, const float* __restrict__ xs,
    const u16* __restrict__ Knm, const u16* __restrict__ Vcm,
    u16* __restrict__ xcat) {
  __shared__ __align__(16) u16 SMEM[9728];  // 19456 B
  const int b = blockIdx.y, q0 = blockIdx.x * 32;
  const int t = threadIdx.x;
  const int wq = t >> 6, lane = t & 63, lq = lane & 15, quad = lane >> 4;
  const int wb = wq * 32;  // wave's key-slice base within a 128-key tile
  const float* xub = xu + (size_t)b * 128 * HW;
  const float* xsb = xs + (size_t)b * 128 * HW;
  const u16* Kb = Knm + (size_t)b * HW * 64;
  const u16* Vb = Vcm + (size_t)b * 64 * HW;
  u16* Pw = SMEM + wq * 32 * 36;  // wave-private P (q,k) tile, 2304 B

  // Q B-fragments: 32 q x 64 ch per wave (B[n=q][k=ch])
  bh8 qb[2][2];
#pragma unroll
  for (int nt = 0; nt < 2; ++nt)
#pragma unroll
    for (int s = 0; s < 2; ++s)
#pragma unroll
      for (int j = 0; j < 8; ++j) {
        int ch = s * 32 + quad * 8 + j;
        qb[nt][s][j] = (short)f2bf(xub[(size_t)ch * HW + q0 + nt * 16 + lq]);
      }

  f32x4 O[4][2];  // [ct: ch-tile][nt: q-tile], C: row=ch_local, col=q_local
#pragma unroll
  for (int ct = 0; ct < 4; ++ct)
#pragma unroll
    for (int nt = 0; nt < 2; ++nt) O[ct][nt] = (f32x4)(0.f);
  float lsum[2] = {0.f, 0.f};

  bh8 kfa[4], vfa[4], kfb[4], vfb[4];
  LOADKV(0, kfa, vfa);
  for (int kb = 0; kb < 32; kb += 2) {
    LOADKV(kb + 1, kfb, vfb);
    attn_step(kfa, vfa, qb, O, lsum, Pw, lq, quad);
    if (kb + 2 < 32) LOADKV(kb + 2, kfa, vfa);
    attn_step(kfb, vfb, qb, O, lsum, Pw, lq, quad);
  }

  // ---- epilogue: cross-wave reduce, normalize, shortcut, bf16 store ----
#pragma unroll
  for (int nt = 0; nt < 2; ++nt) {
    lsum[nt] += __shfl_xor(lsum[nt], 16);
    lsum[nt] += __shfl_xor(lsum[nt], 32);
  }
  __syncthreads();  // all waves done with their Pw before SMEM reuse
  float* Posc = (float*)SMEM;            // [4 waves][32 ch][36 q] = 18432 B
  float* Lred = (float*)(SMEM + 9216);   // [4 waves][32 q] = 512 B
  if (quad == 0) {
#pragma unroll
    for (int nt = 0; nt < 2; ++nt) Lred[wq * 32 + nt * 16 + lq] = lsum[nt];
  }

  const int q = t & 31, cg = t >> 5;  // 8 ch-groups of 4 channels
#pragma unroll
  for (int rh = 0; rh < 2; ++rh) {
    if (rh) __syncthreads();  // previous half's readers done
    // write this wave's fp32 partials for ch half rh
#pragma unroll
    for (int c2 = 0; c2 < 2; ++c2)
#pragma unroll
      for (int nt = 0; nt < 2; ++nt)
#pragma unroll
        for (int r = 0; r < 4; ++r)
          Posc[(wq * 32 + c2 * 16 + quad * 4 + r) * 36 + nt * 16 + lq] =
              O[rh * 2 + c2][nt][r];
    __syncthreads();
    float li = Lred[q] + Lred[32 + q] + Lred[64 + q] + Lred[96 + q];
    float inv = 1.f / li;
    u16 h[4];
#pragma unroll
    for (int i = 0; i < 4; ++i) {
      int chl = cg * 4 + i;
      float s = 0.f;
#pragma unroll
      for (int w2 = 0; w2 < 4; ++w2) s += Posc[(w2 * 32 + chl) * 36 + q];
      int ch = rh * 32 + chl;
      size_t g = (size_t)ch * HW + q0 + q;
      h[i] = f2bf(s * inv + xub[g] + xsb[g]);
    }
    u32 pk0 = (u32)h[0] | ((u32)h[1] << 16);
    u32 pk1 = (u32)h[2] | ((u32)h[3] << 16);
    u16* ob = xcat + ((size_t)b * HW + q0 + q) * 128 + rh * 32 + cg * 4;
    *(uint2*)ob = make_uint2(pk0, pk1);
  }
}

// ---------------------------------------------------------------------------
// Channel gram partials: Mp[chunk][b][c][d] = sum over 128 n of u2[c,n]k2[d,n]
// grid (32 nchunk, 8 b), block 256.
// ---------------------------------------------------------------------------
__global__ __launch_bounds__(256) void chan_gram(
    const float* __restrict__ xu, const float* __restrict__ K2t,
    float* __restrict__ Mp) {
  __shared__ float Us[64][65], Ksm[64][65];
  const int b = blockIdx.y, n0 = blockIdx.x * 128;
  const int t = threadIdx.x, c = t & 63, dg = t >> 6;
  const float* ub = xu + ((size_t)b * 128 + 64) * HW;
  const float* kb = K2t + (size_t)b * 64 * HW;
  float acc[16];
#pragma unroll
  for (int i = 0; i < 16; ++i) acc[i] = 0.f;
  for (int s = 0; s < 2; ++s) {
    int nn = n0 + s * 64;
    __syncthreads();
    for (int r = 0; r < 16; ++r) {
      int row = r * 4 + dg;
      Us[row][c] = ub[(size_t)row * HW + nn + c];
      Ksm[row][c] = kb[(size_t)row * HW + nn + c];
    }
    __syncthreads();
    for (int n = 0; n < 64; ++n) {
      float u = Us[c][n];
#pragma unroll
      for (int i = 0; i < 16; ++i) acc[i] = fmaf(Ksm[dg * 16 + i][n], u, acc[i]);
    }
  }
  float* dst = Mp + ((size_t)blockIdx.x * 8 + b) * 4096 + c * 64 + dg * 16;
#pragma unroll
  for (int i = 0; i < 16; ++i) dst[i] = acc[i];
}

// reduce 32 chunk-partials -> M. grid 128, block 256.
__global__ void chan_reduce(const float* __restrict__ Mp, float* __restrict__ M) {
  int idx = blockIdx.x * 256 + threadIdx.x;  // 32768 cells
  float s = 0.f;
  for (int ch = 0; ch < 32; ++ch) s += Mp[(size_t)ch * 32768 + idx];
  M[idx] = s;
}

// ---------------------------------------------------------------------------
// chan_apply with fused softmax: A = softmax_c(M[b]) computed in-block, then
// cout[n][d] = sum_c v2[n][c]*A[c][d]; + shortcut2; bf16 n-major store.
// grid (64 nblk, 8 b), block 256
// ---------------------------------------------------------------------------
__global__ __launch_bounds__(256) void chan_apply(
    const float* __restrict__ V2t, const float* __restrict__ M,
    const float* __restrict__ xu, const float* __restrict__ xs,
    u16* __restrict__ xcat) {
  __shared__ float Vsm[64][65];
  __shared__ float As[64][65];
  __shared__ float red1[4][64], red2[4][64];
  const int b = blockIdx.y, n0 = blockIdx.x * 64, t = threadIdx.x;
  const int lane = t & 63, dg = t >> 6;
  const float* Vb = V2t + (size_t)b * 64 * HW;
  for (int s = 0; s < 16; ++s) {
    int c = s * 4 + dg;
    Vsm[lane][c] = Vb[(size_t)c * HW + n0 + lane];
  }
  for (int idx = t; idx < 4096; idx += 256) As[idx >> 6][idx & 63] = M[b * 4096 + idx];
  __syncthreads();
  // softmax over c per d=lane; this thread owns c in [dg*16, dg*16+16)
  float mx = -1e30f;
#pragma unroll
  for (int i = 0; i < 16; ++i) mx = fmaxf(mx, As[dg * 16 + i][lane]);
  red1[dg][lane] = mx;
  __syncthreads();
  mx = fmaxf(fmaxf(red1[0][lane], red1[1][lane]), fmaxf(red1[2][lane], red1[3][lane]));
  float se = 0.f;
#pragma unroll
  for (int i = 0; i < 16; ++i) {
    float e = __expf(As[dg * 16 + i][lane] - mx);
    As[dg * 16 + i][lane] = e;  // own cells only
    se += e;
  }
  red2[dg][lane] = se;
  __syncthreads();

  float acc[16];
#pragma unroll
  for (int i = 0; i < 16; ++i) acc[i] = 0.f;
  for (int c = 0; c < 64; ++c) {
    float v = Vsm[lane][c];
#pragma unroll
    for (int i = 0; i < 16; ++i) acc[i] = fmaf(v, As[c][dg * 16 + i], acc[i]);
  }
  const float* xub = xu + ((size_t)b * 128 + 64) * HW;
  const float* xsb = xs + ((size_t)b * 128 + 64) * HW;
  const int n = n0 + lane;
  u16 hv[16];
#pragma unroll
  for (int i = 0; i < 16; ++i) {
    int d = dg * 16 + i;
    float sm = red2[0][d] + red2[1][d] + red2[2][d] + red2[3][d];
    hv[i] = f2bf(acc[i] / sm + xub[(size_t)d * HW + n] + xsb[(size_t)d * HW + n]);
  }
  u32 pk[8];
#pragma unroll
  for (int j = 0; j < 8; ++j) pk[j] = (u32)hv[2 * j] | ((u32)hv[2 * j + 1] << 16);
  u16* ob = xcat + ((size_t)b * HW + n) * 128 + 64 + dg * 16;
  *(uint4*)(ob) = make_uint4(pk[0], pk[1], pk[2], pk[3]);
  *(uint4*)(ob + 8) = make_uint4(pk[4], pk[5], pk[6], pk[7]);
}

// ---------------------------------------------------------------------------
// Implicit-GEMM 3x3 conv via bf16 MFMA + fused BN(folded) + ReLU.
// Block: 512 thr = 8 waves (2 waves/SIMD). Tile: 128 spatial x 128 oc.
// Wave wq: m-tiles {2*(wq>>1), 2*(wq>>1)+1} x oc-half (wq&1)*64 (4 nt).
// grid (32 hblk, 8 b)
// ---------------------------------------------------------------------------
__global__ __launch_bounds__(512) void conv_mfma(
    const u16* __restrict__ X, const u16* __restrict__ Wg,
    const float* __restrict__ shb, float* __restrict__ out) {
  __shared__ __align__(16) u16 In[4 * 66 * 136];
  __shared__ __align__(16) u16 Wt[2][128 * 136];
  const int b = blockIdx.y, h0 = blockIdx.x * 2;
  const int t = threadIdx.x;
  const int wq = t >> 6, lane = t & 63, lq = lane & 15, quad = lane >> 4;
  const int nb = (wq & 1) * 64;       // oc-half base
  const int mb = (wq >> 1) * 2;       // m-tile pair base
  const u16* Xb = X + (size_t)b * HW * 128;

  // zero w-halo cells (iw = 0 and 65 for each ih)
  if (t < 128) {
    int ih = t >> 5, iwsel = (t >> 4) & 1, ck = t & 15;
    int iw = iwsel ? 65 : 0;
    *(uint4*)&In[(ih * 66 + iw) * 136 + ck * 8] = make_uint4(0, 0, 0, 0);
  }
  // stage input rows (zero h-halo out of range); 512 threads
  for (int ih = 0; ih < 4; ++ih) {
    int h = h0 - 1 + ih;
    bool ok = (h >= 0 && h < 64);
    const u16* src = Xb + (size_t)h * 64 * 128;
#pragma unroll
    for (int p = 0; p < 2; ++p) {
      int idx = p * 512 + t;
      int row = idx >> 4, ck = idx & 15;
      uint4 d = make_uint4(0, 0, 0, 0);
      if (ok) d = *(const uint4*)(src + (size_t)row * 128 + ck * 8);
      *(uint4*)&In[(ih * 66 + 1 + row) * 136 + ck * 8] = d;
    }
  }
  // stage tap-0 weights into buffer 0 (2048 uint4 over 512 threads = 4 passes)
  {
    const u16* src = Wg;
#pragma unroll
    for (int p = 0; p < 4; ++p) {
      int idx = p * 512 + t;
      int oc = idx >> 4, ck = idx & 15;
      uint4 d = *(const uint4*)(src + oc * 128 + ck * 8);
      *(uint4*)&Wt[0][oc * 136 + ck * 8] = d;
    }
  }
  __syncthreads();

  f32x4 acc[2][4];
#pragma unroll
  for (int mt = 0; mt < 2; ++mt)
#pragma unroll
    for (int nt = 0; nt < 4; ++nt) acc[mt][nt] = (f32x4)(0.f);

  for (int tap = 0; tap < 9; ++tap) {
    const int cur = tap & 1;
    if (tap < 8) {  // prefetch next tap into the other buffer
      const u16* src = Wg + (size_t)(tap + 1) * 128 * 128;
#pragma unroll
      for (int p = 0; p < 4; ++p) {
        int idx = p * 512 + t;
        int oc = idx >> 4, ck = idx & 15;
        uint4 d = *(const uint4*)(src + oc * 128 + ck * 8);
        *(uint4*)&Wt[cur ^ 1][oc * 136 + ck * 8] = d;
      }
    }
    const int dh = tap / 3, dw = tap - 3 * dh;
    const u16* Wc = &Wt[cur][0];
#pragma unroll
    for (int c = 0; c < 4; ++c) {
      bh8 bf[4];
#pragma unroll
      for (int nt = 0; nt < 4; ++nt)
        bf[nt] = *(const bh8*)&Wc[(nb + nt * 16 + lq) * 136 + c * 32 + quad * 8];
#pragma unroll
      for (int mt = 0; mt < 2; ++mt) {
        int s = (mb + mt) * 16 + lq;
        int ih = (s >> 6) + dh, iw = (s & 63) + dw;
        bh8 af = *(const bh8*)&In[(ih * 66 + iw) * 136 + c * 32 + quad * 8];
#pragma unroll
        for (int nt = 0; nt < 4; ++nt)
          acc[mt][nt] = __builtin_amdgcn_mfma_f32_16x16x32_bf16(af, bf[nt], acc[mt][nt], 0, 0, 0);
      }
    }
    __syncthreads();
  }

  // epilogue: +bias, ReLU, dense float4 stores
  float shv[4];
#pragma unroll
  for (int nt = 0; nt < 4; ++nt) shv[nt] = shb[nb + nt * 16 + lq];
#pragma unroll
  for (int mt = 0; mt < 2; ++mt) {
    int mtile = mb + mt;
    int h = h0 + (mtile >> 2);
    int w0 = ((mtile & 3) * 16) + quad * 4;
#pragma unroll
    for (int nt = 0; nt < 4; ++nt) {
      int oc = nb + nt * 16 + lq;
      float4 v;
      v.x = fmaxf(acc[mt][nt][0] + shv[nt], 0.f);
      v.y = fmaxf(acc[mt][nt][1] + shv[nt], 0.f);
      v.z = fmaxf(acc[mt][nt][2] + shv[nt], 0.f);
      v.w = fmaxf(acc[mt][nt][3] + shv[nt], 0.f);
      *(float4*)&out[((size_t)b * 128 + oc) * HW + h * 64 + w0] = v;
    }
  }
}

// ---------------------------------------------------------------------------
extern "C" void kernel_launch(void* const* d_in, const int* in_sizes, int n_in,
                              void* d_out, int out_size, void* d_ws, size_t ws_size,
                              hipStream_t stream) {
  const float* x_up   = (const float*)d_in[0];
  const float* x_skip = (const float*)d_in[1];
  const float* kv1_w  = (const float*)d_in[2];
  const float* kv1_b  = (const float*)d_in[3];
  const float* kv2_w  = (const float*)d_in[4];
  const float* kv2_b  = (const float*)d_in[5];
  const float* conv_w = (const float*)d_in[6];
  const float* bn_g   = (const float*)d_in[7];
  const float* bn_b   = (const float*)d_in[8];
  const float* bn_m   = (const float*)d_in[9];
  const float* bn_v   = (const float*)d_in[10];
  float* out = (float*)d_out;

  char* ws = (char*)d_ws;
  const size_t XCATB_B = (size_t)8 * HW * 128 * 2;  // 8.39 MB bf16 n-major
  const size_t KV32_B  = (size_t)8 * 64 * HW * 4;   // 8.39 MB
  const size_t KV16_B  = (size_t)8 * 64 * HW * 2;   // 4.19 MB
  size_t off = 0;
  u16*   xcat = (u16*)(ws + off);   off += XCATB_B;
  float* K2t  = (float*)(ws + off); off += KV32_B;
  float* V2t  = (float*)(ws + off); off += KV32_B;
  u32*   Knm  = (u32*)(ws + off);   off += KV16_B;
  u16*   Vcm  = (u16*)(ws + off);   off += KV16_B;
  float* Mp   = (float*)(ws + off); off += (size_t)32 * 8 * 4096 * 4;
  float* M    = (float*)(ws + off); off += (size_t)8 * 4096 * 4;
  u16*   Wg   = (u16*)(ws + off);   off += (size_t)9 * 128 * 128 * 2;
  float* shb  = (float*)(ws + off); off += 512;

  kv_proj<<<dim3(64, 8), 256, 0, stream>>>(x_skip, kv1_w, kv1_b, kv2_w, kv2_b,
                                           Knm, Vcm, K2t, V2t,
                                           conv_w, bn_g, bn_b, bn_m, bn_v, Wg, shb);
  attn_mfma<<<dim3(128, 8), 256, 0, stream>>>(x_up, x_skip, (const u16*)Knm, Vcm, xcat);
  chan_gram<<<dim3(32, 8), 256, 0, stream>>>(x_up, K2t, Mp);
  chan_reduce<<<128, 256, 0, stream>>>(Mp, M);
  chan_apply<<<dim3(64, 8), 256, 0, stream>>>(V2t, M, x_up, x_skip, xcat);
  conv_mfma<<<dim3(32, 8), 512, 0, stream>>>(xcat, Wg, shb, out);
}

// Round 10
// 274.452 us; speedup vs baseline: 2.0624x; 1.1848x over previous
//
#include <hip/hip_runtime.h>
#include <math.h>

#define HW 4096

typedef __attribute__((ext_vector_type(8))) short bh8;
typedef __attribute__((ext_vector_type(4))) float f32x4;
typedef unsigned int u32;
typedef unsigned short u16;

__device__ __forceinline__ u16 f2bf(float f) {
  union { float f; u32 u; } v; v.f = f;
  u32 u = v.u;
  return (u16)((u + 0x7FFFu + ((u >> 16) & 1u)) >> 16);
}
__device__ __forceinline__ float bf2f(u16 h) {
  union { u32 u; float f; } v; v.u = ((u32)h) << 16;
  return v.f;
}

// ---------------------------------------------------------------------------
// kv projection (+ fused conv-weight convert prologue).
// Branch 1 (spatial attn): K1 -> bf16 n-major (b,4096,64), V1 -> bf16
// ch-major (b,64,4096). Branch 2 (channel attn): bf16 ch-major.
// grid (64 nblk, 8 b), block 256
// ---------------------------------------------------------------------------
__global__ __launch_bounds__(256) void kv_proj(
    const float* __restrict__ xs,
    const float* __restrict__ w1, const float* __restrict__ b1,
    const float* __restrict__ w2, const float* __restrict__ b2,
    u32* __restrict__ Knm, u16* __restrict__ Vcm,
    u16* __restrict__ K2t, u16* __restrict__ V2t,
    const float* __restrict__ cw, const float* __restrict__ gamma,
    const float* __restrict__ beta, const float* __restrict__ mean,
    const float* __restrict__ var, u16* __restrict__ Wg,
    float* __restrict__ shb) {
  __shared__ float Ss[64][65];
  __shared__ float Ws[128 * 64];
  __shared__ u32 LtK[64][33];  // packed bf16x2 K rows, conflict-free pitch
  const int b = blockIdx.y, n0 = blockIdx.x * 64;
  const int t = threadIdx.x;
  const int lane_n = t & 63, jg = t >> 6;
  const int jbase = jg * 32;
  const float* xsb = xs + (size_t)b * 128 * HW;

  // ---- fused wcvt: conv_w (oc,ic,3,3) -> Wg[tap][oc][ic] bf16, BN folded ----
  {
    int gid = (blockIdx.y * 64 + blockIdx.x) * 256 + t;  // 0..131071
    for (int i = gid; i < 147456; i += 131072) {
      int tap = i >> 14, oc = (i >> 7) & 127, ic = i & 127;
      float sc = gamma[oc] * rsqrtf(var[oc] + 1e-5f);
      Wg[i] = f2bf(cw[((size_t)(oc * 128 + ic)) * 9 + tap] * sc);
    }
    if (gid < 128) {
      float sc = gamma[gid] * rsqrtf(var[gid] + 1e-5f);
      shb[gid] = beta[gid] - mean[gid] * sc;
    }
  }

  for (int br = 0; br < 2; ++br) {
    const float* W = br ? w2 : w1;
    const float* bias = br ? b2 : b1;
    const float* src = xsb + (br ? 64 * HW : 0);
    __syncthreads();
    for (int s = 0; s < 16; ++s) {
      int ch = s * 4 + jg;
      Ss[ch][lane_n] = src[(size_t)ch * HW + n0 + lane_n];
    }
    for (int i = t; i < 128 * 64; i += 256) Ws[i] = W[i];
    __syncthreads();

    float acc[32];
#pragma unroll
    for (int i = 0; i < 32; ++i) acc[i] = bias[jbase + i];
    for (int ch = 0; ch < 64; ++ch) {
      float s = Ss[ch][lane_n];
#pragma unroll
      for (int i = 0; i < 32; ++i) acc[i] = fmaf(Ws[(jbase + i) * 64 + ch], s, acc[i]);
    }

    if (br == 0) {
      if (jg < 2) {  // K channels jbase..jbase+31 -> pack to LDS
#pragma unroll
        for (int i2 = 0; i2 < 16; ++i2) {
          u32 p = (u32)f2bf(acc[2 * i2]) | ((u32)f2bf(acc[2 * i2 + 1]) << 16);
          LtK[lane_n][jg * 16 + i2] = p;
        }
      } else {  // V channels (jbase-64)..+31 -> bf16 ch-major global
#pragma unroll
        for (int i = 0; i < 32; ++i) {
          int ch = jbase - 64 + i;
          Vcm[((size_t)b * 64 + ch) * HW + n0 + lane_n] = f2bf(acc[i]);
        }
      }
      __syncthreads();
      // coalesced n-major K write: rows of 32 uints (64 bf16)
#pragma unroll
      for (int p = 0; p < 8; ++p) {
        int idx = p * 256 + t;
        int n = idx >> 5, cc = idx & 31;
        Knm[((size_t)b * HW + n0 + n) * 32 + cc] = LtK[n][cc];
      }
    } else {  // channel branch: bf16 ch-major K2t/V2t
      u16* Kt = K2t + (size_t)b * 64 * HW;
      u16* Vt = V2t + (size_t)b * 64 * HW;
#pragma unroll
      for (int i = 0; i < 32; ++i) {
        int j = jbase + i;
        u16* dst = (j < 64) ? (Kt + (size_t)j * HW) : (Vt + (size_t)(j - 64) * HW);
        dst[n0 + lane_n] = f2bf(acc[i]);
      }
    }
  }
}

// ---------------------------------------------------------------------------
// Fused dispatch: blocks x<64 run MFMA flash attention (r6 structure —
// 64-q blocks, key-sliced waves, barrier-free K-loop, direct global->VGPR
// K/V with 2-deep register dbuf, exp(S-12), single wave-private P LDS
// roundtrip); blocks x>=64 run chan_gram partials (bf16 K2t). Merging fills
// the machine (512 attn + 256 gram blocks) and saves a launch.
// grid (96, 8 b), block 256
// ---------------------------------------------------------------------------
__device__ __forceinline__ void attn_step(
    const bh8* kf, const bh8* vf, const bh8 (&qb)[4][2],
    f32x4 (&O)[4][4], float (&lsum)[4], u16* Pw, int lq, int quad) {
  f32x4 S[2][4];
#pragma unroll
  for (int mt = 0; mt < 2; ++mt)
#pragma unroll
    for (int nt = 0; nt < 4; ++nt) {
      f32x4 a = (f32x4)(0.f);
      a = __builtin_amdgcn_mfma_f32_16x16x32_bf16(kf[mt * 2 + 0], qb[nt][0], a, 0, 0, 0);
      a = __builtin_amdgcn_mfma_f32_16x16x32_bf16(kf[mt * 2 + 1], qb[nt][1], a, 0, 0, 0);
      S[mt][nt] = a;
    }
#pragma unroll
  for (int mt = 0; mt < 2; ++mt)
#pragma unroll
    for (int nt = 0; nt < 4; ++nt) {
      float p0 = __expf(S[mt][nt][0] - 12.f);
      float p1 = __expf(S[mt][nt][1] - 12.f);
      float p2 = __expf(S[mt][nt][2] - 12.f);
      float p3 = __expf(S[mt][nt][3] - 12.f);
      lsum[nt] += (p0 + p1) + (p2 + p3);
      u32 lo = (u32)f2bf(p0) | ((u32)f2bf(p1) << 16);
      u32 hi = (u32)f2bf(p2) | ((u32)f2bf(p3) << 16);
      *(uint2*)&Pw[(nt * 16 + lq) * 36 + mt * 16 + quad * 4] = make_uint2(lo, hi);
    }
#pragma unroll
  for (int nt = 0; nt < 4; ++nt) {
    bh8 pb = *(const bh8*)&Pw[(nt * 16 + lq) * 36 + quad * 8];
#pragma unroll
    for (int ct = 0; ct < 4; ++ct)
      O[ct][nt] = __builtin_amdgcn_mfma_f32_16x16x32_bf16(vf[ct], pb, O[ct][nt], 0, 0, 0);
  }
}

#define LOADKV(KB, KF, VF)                                            \
  do {                                                                \
    const int n0_ = (KB) * 128;                                       \
    const u16* kr_ = Kb + (size_t)(n0_ + wb + lq) * 64 + quad * 8;    \
    KF[0] = *(const bh8*)(kr_);                                       \
    KF[1] = *(const bh8*)(kr_ + 32);                                  \
    KF[2] = *(const bh8*)(kr_ + 1024);                                \
    KF[3] = *(const bh8*)(kr_ + 1056);                                \
    const u16* vr_ = Vb + (size_t)lq * HW + n0_ + wb + quad * 8;      \
    VF[0] = *(const bh8*)(vr_);                                       \
    VF[1] = *(const bh8*)(vr_ + 16 * HW);                             \
    VF[2] = *(const bh8*)(vr_ + 32 * HW);                             \
    VF[3] = *(const bh8*)(vr_ + 48 * HW);                             \
  } while (0)

__global__ __launch_bounds__(256, 2) void attn_gram(
    const float* __restrict__ xu, const float* __restrict__ xs,
    const u16* __restrict__ Knm, const u16* __restrict__ Vcm,
    u16* __restrict__ xcat,
    const u16* __restrict__ K2t, float* __restrict__ Mp) {
  __shared__ __align__(16) u16 SMEM[18432];  // 36864 B (attn) / 33280 B (gram)
  const int b = blockIdx.y;
  const int t = threadIdx.x;

  if (blockIdx.x >= 64) {
    // ---------------- chan_gram path ----------------
    float* Us = (float*)SMEM;      // [64][65]
    float* Ksm = Us + 64 * 65;     // [64][65]
    const int n0 = (blockIdx.x - 64) * 128;
    const int c = t & 63, dg = t >> 6;
    const float* ub = xu + ((size_t)b * 128 + 64) * HW;
    const u16* kb2 = K2t + (size_t)b * 64 * HW;
    float acc[16];
#pragma unroll
    for (int i = 0; i < 16; ++i) acc[i] = 0.f;
    for (int s = 0; s < 2; ++s) {
      int nn = n0 + s * 64;
      __syncthreads();
      for (int r = 0; r < 16; ++r) {
        int row = r * 4 + dg;
        Us[row * 65 + c] = ub[(size_t)row * HW + nn + c];
        Ksm[row * 65 + c] = bf2f(kb2[(size_t)row * HW + nn + c]);
      }
      __syncthreads();
      for (int n = 0; n < 64; ++n) {
        float u = Us[c * 65 + n];
#pragma unroll
        for (int i = 0; i < 16; ++i)
          acc[i] = fmaf(Ksm[(dg * 16 + i) * 65 + n], u, acc[i]);
      }
    }
    float* dst = Mp + ((size_t)(blockIdx.x - 64) * 8 + b) * 4096 + c * 64 + dg * 16;
#pragma unroll
    for (int i = 0; i < 16; ++i) dst[i] = acc[i];
    return;
  }

  // ---------------- attention path (r6 structure) ----------------
  const int q0 = blockIdx.x * 64;
  const int wq = t >> 6, lane = t & 63, lq = lane & 15, quad = lane >> 4;
  const int wb = wq * 32;  // wave's key-slice base within a 128-key tile
  const float* xub = xu + (size_t)b * 128 * HW;
  const float* xsb = xs + (size_t)b * 128 * HW;
  const u16* Kb = Knm + (size_t)b * HW * 64;
  const u16* Vb = Vcm + (size_t)b * 64 * HW;
  u16* Pw = SMEM + wq * 64 * 36;  // wave-private P (q,k) tile

  // Q B-fragments: all 64 q x 64 ch per wave (B[n=q][k=ch])
  bh8 qb[4][2];
#pragma unroll
  for (int nt = 0; nt < 4; ++nt)
#pragma unroll
    for (int s = 0; s < 2; ++s)
#pragma unroll
      for (int j = 0; j < 8; ++j) {
        int ch = s * 32 + quad * 8 + j;
        qb[nt][s][j] = (short)f2bf(xub[(size_t)ch * HW + q0 + nt * 16 + lq]);
      }

  f32x4 O[4][4];  // [ct: ch-tile][nt: q-tile], C: row=ch_local, col=q_local
#pragma unroll
  for (int ct = 0; ct < 4; ++ct)
#pragma unroll
    for (int nt = 0; nt < 4; ++nt) O[ct][nt] = (f32x4)(0.f);
  float lsum[4] = {0.f, 0.f, 0.f, 0.f};

  bh8 kfa[4], vfa[4], kfb[4], vfb[4];
  LOADKV(0, kfa, vfa);
  for (int kb = 0; kb < 32; kb += 2) {
    LOADKV(kb + 1, kfb, vfb);
    attn_step(kfa, vfa, qb, O, lsum, Pw, lq, quad);
    if (kb + 2 < 32) LOADKV(kb + 2, kfa, vfa);
    attn_step(kfb, vfb, qb, O, lsum, Pw, lq, quad);
  }

  // ---- epilogue: cross-wave reduce, normalize, shortcut, bf16 store ----
#pragma unroll
  for (int nt = 0; nt < 4; ++nt) {
    lsum[nt] += __shfl_xor(lsum[nt], 16);
    lsum[nt] += __shfl_xor(lsum[nt], 32);
  }
  __syncthreads();  // all waves done with their Pw before SMEM reuse
  float* Posc = (float*)SMEM;            // [4 waves][32 ch][68 q] = 34816 B
  float* Lred = (float*)(SMEM + 17408);  // [4 waves][4 nt][16 lq] = 1024 B
  if (quad == 0) {
#pragma unroll
    for (int nt = 0; nt < 4; ++nt) Lred[(wq * 4 + nt) * 16 + lq] = lsum[nt];
  }

  const int q = t & 63, cg = t >> 6;
#pragma unroll
  for (int rh = 0; rh < 2; ++rh) {
    if (rh) __syncthreads();  // previous half's readers done
#pragma unroll
    for (int c2 = 0; c2 < 2; ++c2)
#pragma unroll
      for (int nt = 0; nt < 4; ++nt)
#pragma unroll
        for (int r = 0; r < 4; ++r)
          Posc[(wq * 32 + c2 * 16 + quad * 4 + r) * 68 + nt * 16 + lq] =
              O[rh * 2 + c2][nt][r];
    __syncthreads();
    float li = 0.f;
#pragma unroll
    for (int w2 = 0; w2 < 4; ++w2) li += Lred[w2 * 64 + q];
    float inv = 1.f / li;
    u16 h[8];
#pragma unroll
    for (int i = 0; i < 8; ++i) {
      int chl = cg * 8 + i;
      float s = 0.f;
#pragma unroll
      for (int w2 = 0; w2 < 4; ++w2) s += Posc[(w2 * 32 + chl) * 68 + q];
      int ch = rh * 32 + chl;
      size_t g = (size_t)ch * HW + q0 + q;
      h[i] = f2bf(s * inv + xub[g] + xsb[g]);
    }
    u32 pk[4];
#pragma unroll
    for (int j = 0; j < 4; ++j) pk[j] = (u32)h[2 * j] | ((u32)h[2 * j + 1] << 16);
    u16* ob = xcat + ((size_t)b * HW + q0 + q) * 128 + rh * 32 + cg * 8;
    *(uint4*)ob = make_uint4(pk[0], pk[1], pk[2], pk[3]);
  }
}

// reduce 32 chunk-partials -> M. grid 128, block 256.
__global__ void chan_reduce(const float* __restrict__ Mp, float* __restrict__ M) {
  int idx = blockIdx.x * 256 + threadIdx.x;  // 32768 cells
  float s = 0.f;
  for (int ch = 0; ch < 32; ++ch) s += Mp[(size_t)ch * 32768 + idx];
  M[idx] = s;
}

// ---------------------------------------------------------------------------
// chan_apply with fused softmax: A = softmax_c(M[b]) computed in-block, then
// cout[n][d] = sum_c v2[n][c]*A[c][d]; + shortcut2; bf16 n-major store.
// V2t is bf16 (converted to fp32 at LDS staging). grid (64 nblk, 8 b), 256
// ---------------------------------------------------------------------------
__global__ __launch_bounds__(256) void chan_apply(
    const u16* __restrict__ V2t, const float* __restrict__ M,
    const float* __restrict__ xu, const float* __restrict__ xs,
    u16* __restrict__ xcat) {
  __shared__ float Vsm[64][65];
  __shared__ float As[64][65];
  __shared__ float red1[4][64], red2[4][64];
  const int b = blockIdx.y, n0 = blockIdx.x * 64, t = threadIdx.x;
  const int lane = t & 63, dg = t >> 6;
  const u16* Vb = V2t + (size_t)b * 64 * HW;
  for (int s = 0; s < 16; ++s) {
    int c = s * 4 + dg;
    Vsm[lane][c] = bf2f(Vb[(size_t)c * HW + n0 + lane]);
  }
  for (int idx = t; idx < 4096; idx += 256) As[idx >> 6][idx & 63] = M[b * 4096 + idx];
  __syncthreads();
  // softmax over c per d=lane; this thread owns c in [dg*16, dg*16+16)
  float mx = -1e30f;
#pragma unroll
  for (int i = 0; i < 16; ++i) mx = fmaxf(mx, As[dg * 16 + i][lane]);
  red1[dg][lane] = mx;
  __syncthreads();
  mx = fmaxf(fmaxf(red1[0][lane], red1[1][lane]), fmaxf(red1[2][lane], red1[3][lane]));
  float se = 0.f;
#pragma unroll
  for (int i = 0; i < 16; ++i) {
    float e = __expf(As[dg * 16 + i][lane] - mx);
    As[dg * 16 + i][lane] = e;  // own cells only
    se += e;
  }
  red2[dg][lane] = se;
  __syncthreads();

  float acc[16];
#pragma unroll
  for (int i = 0; i < 16; ++i) acc[i] = 0.f;
  for (int c = 0; c < 64; ++c) {
    float v = Vsm[lane][c];
#pragma unroll
    for (int i = 0; i < 16; ++i) acc[i] = fmaf(v, As[c][dg * 16 + i], acc[i]);
  }
  const float* xub = xu + ((size_t)b * 128 + 64) * HW;
  const float* xsb = xs + ((size_t)b * 128 + 64) * HW;
  const int n = n0 + lane;
  u16 hv[16];
#pragma unroll
  for (int i = 0; i < 16; ++i) {
    int d = dg * 16 + i;
    float sm = red2[0][d] + red2[1][d] + red2[2][d] + red2[3][d];
    hv[i] = f2bf(acc[i] / sm + xub[(size_t)d * HW + n] + xsb[(size_t)d * HW + n]);
  }
  u32 pk[8];
#pragma unroll
  for (int j = 0; j < 8; ++j) pk[j] = (u32)hv[2 * j] | ((u32)hv[2 * j + 1] << 16);
  u16* ob = xcat + ((size_t)b * HW + n) * 128 + 64 + dg * 16;
  *(uint4*)(ob) = make_uint4(pk[0], pk[1], pk[2], pk[3]);
  *(uint4*)(ob + 8) = make_uint4(pk[4], pk[5], pk[6], pk[7]);
}

// ---------------------------------------------------------------------------
// Implicit-GEMM 3x3 conv via bf16 MFMA + fused BN(folded) + ReLU.
// Block: 512 thr = 8 waves (2 waves/SIMD). Tile: 128 spatial x 128 oc.
// Wave wq: m-tiles {2*(wq>>1), 2*(wq>>1)+1} x oc-half (wq&1)*64 (4 nt).
// grid (32 hblk, 8 b)
// ---------------------------------------------------------------------------
__global__ __launch_bounds__(512) void conv_mfma(
    const u16* __restrict__ X, const u16* __restrict__ Wg,
    const float* __restrict__ shb, float* __restrict__ out) {
  __shared__ __align__(16) u16 In[4 * 66 * 136];
  __shared__ __align__(16) u16 Wt[2][128 * 136];
  const int b = blockIdx.y, h0 = blockIdx.x * 2;
  const int t = threadIdx.x;
  const int wq = t >> 6, lane = t & 63, lq = lane & 15, quad = lane >> 4;
  const int nb = (wq & 1) * 64;       // oc-half base
  const int mb = (wq >> 1) * 2;       // m-tile pair base
  const u16* Xb = X + (size_t)b * HW * 128;

  // zero w-halo cells (iw = 0 and 65 for each ih)
  if (t < 128) {
    int ih = t >> 5, iwsel = (t >> 4) & 1, ck = t & 15;
    int iw = iwsel ? 65 : 0;
    *(uint4*)&In[(ih * 66 + iw) * 136 + ck * 8] = make_uint4(0, 0, 0, 0);
  }
  // stage input rows (zero h-halo out of range); 512 threads
  for (int ih = 0; ih < 4; ++ih) {
    int h = h0 - 1 + ih;
    bool ok = (h >= 0 && h < 64);
    const u16* src = Xb + (size_t)h * 64 * 128;
#pragma unroll
    for (int p = 0; p < 2; ++p) {
      int idx = p * 512 + t;
      int row = idx >> 4, ck = idx & 15;
      uint4 d = make_uint4(0, 0, 0, 0);
      if (ok) d = *(const uint4*)(src + (size_t)row * 128 + ck * 8);
      *(uint4*)&In[(ih * 66 + 1 + row) * 136 + ck * 8] = d;
    }
  }
  // stage tap-0 weights into buffer 0 (2048 uint4 over 512 threads = 4 passes)
  {
    const u16* src = Wg;
#pragma unroll
    for (int p = 0; p < 4; ++p) {
      int idx = p * 512 + t;
      int oc = idx >> 4, ck = idx & 15;
      uint4 d = *(const uint4*)(src + oc * 128 + ck * 8);
      *(uint4*)&Wt[0][oc * 136 + ck * 8] = d;
    }
  }
  __syncthreads();

  f32x4 acc[2][4];
#pragma unroll
  for (int mt = 0; mt < 2; ++mt)
#pragma unroll
    for (int nt = 0; nt < 4; ++nt) acc[mt][nt] = (f32x4)(0.f);

  for (int tap = 0; tap < 9; ++tap) {
    const int cur = tap & 1;
    if (tap < 8) {  // prefetch next tap into the other buffer
      const u16* src = Wg + (size_t)(tap + 1) * 128 * 128;
#pragma unroll
      for (int p = 0; p < 4; ++p) {
        int idx = p * 512 + t;
        int oc = idx >> 4, ck = idx & 15;
        uint4 d = *(const uint4*)(src + oc * 128 + ck * 8);
        *(uint4*)&Wt[cur ^ 1][oc * 136 + ck * 8] = d;
      }
    }
    const int dh = tap / 3, dw = tap - 3 * dh;
    const u16* Wc = &Wt[cur][0];
#pragma unroll
    for (int c = 0; c < 4; ++c) {
      bh8 bf[4];
#pragma unroll
      for (int nt = 0; nt < 4; ++nt)
        bf[nt] = *(const bh8*)&Wc[(nb + nt * 16 + lq) * 136 + c * 32 + quad * 8];
#pragma unroll
      for (int mt = 0; mt < 2; ++mt) {
        int s = (mb + mt) * 16 + lq;
        int ih = (s >> 6) + dh, iw = (s & 63) + dw;
        bh8 af = *(const bh8*)&In[(ih * 66 + iw) * 136 + c * 32 + quad * 8];
#pragma unroll
        for (int nt = 0; nt < 4; ++nt)
          acc[mt][nt] = __builtin_amdgcn_mfma_f32_16x16x32_bf16(af, bf[nt], acc[mt][nt], 0, 0, 0);
      }
    }
    __syncthreads();
  }

  // epilogue: +bias, ReLU, dense float4 stores
  float shv[4];
#pragma unroll
  for (int nt = 0; nt < 4; ++nt) shv[nt] = shb[nb + nt * 16 + lq];
#pragma unroll
  for (int mt = 0; mt < 2; ++mt) {
    int mtile = mb + mt;
    int h = h0 + (mtile >> 2);
    int w0 = ((mtile & 3) * 16) + quad * 4;
#pragma unroll
    for (int nt = 0; nt < 4; ++nt) {
      int oc = nb + nt * 16 + lq;
      float4 v;
      v.x = fmaxf(acc[mt][nt][0] + shv[nt], 0.f);
      v.y = fmaxf(acc[mt][nt][1] + shv[nt], 0.f);
      v.z = fmaxf(acc[mt][nt][2] + shv[nt], 0.f);
      v.w = fmaxf(acc[mt][nt][3] + shv[nt], 0.f);
      *(float4*)&out[((size_t)b * 128 + oc) * HW + h * 64 + w0] = v;
    }
  }
}

// ---------------------------------------------------------------------------
extern "C" void kernel_launch(void* const* d_in, const int* in_sizes, int n_in,
                              void* d_out, int out_size, void* d_ws, size_t ws_size,
                              hipStream_t stream) {
  const float* x_up   = (const float*)d_in[0];
  const float* x_skip = (const float*)d_in[1];
  const float* kv1_w  = (const float*)d_in[2];
  const float* kv1_b  = (const float*)d_in[3];
  const float* kv2_w  = (const float*)d_in[4];
  const float* kv2_b  = (const float*)d_in[5];
  const float* conv_w = (const float*)d_in[6];
  const float* bn_g   = (const float*)d_in[7];
  const float* bn_b   = (const float*)d_in[8];
  const float* bn_m   = (const float*)d_in[9];
  const float* bn_v   = (const float*)d_in[10];
  float* out = (float*)d_out;

  char* ws = (char*)d_ws;
  const size_t XCATB_B = (size_t)8 * HW * 128 * 2;  // 8.39 MB bf16 n-major
  const size_t KV16_B  = (size_t)8 * 64 * HW * 2;   // 4.19 MB
  size_t off = 0;
  u16*   xcat = (u16*)(ws + off);   off += XCATB_B;
  u16*   K2t  = (u16*)(ws + off);   off += KV16_B;
  u16*   V2t  = (u16*)(ws + off);   off += KV16_B;
  u32*   Knm  = (u32*)(ws + off);   off += KV16_B;
  u16*   Vcm  = (u16*)(ws + off);   off += KV16_B;
  float* Mp   = (float*)(ws + off); off += (size_t)32 * 8 * 4096 * 4;
  float* M    = (float*)(ws + off); off += (size_t)8 * 4096 * 4;
  u16*   Wg   = (u16*)(ws + off);   off += (size_t)9 * 128 * 128 * 2;
  float* shb  = (float*)(ws + off); off += 512;
  // total ~30 MB

  kv_proj<<<dim3(64, 8), 256, 0, stream>>>(x_skip, kv1_w, kv1_b, kv2_w, kv2_b,
                                           Knm, Vcm, K2t, V2t,
                                           conv_w, bn_g, bn_b, bn_m, bn_v, Wg, shb);
  attn_gram<<<dim3(96, 8), 256, 0, stream>>>(x_up, x_skip, (const u16*)Knm, Vcm,
                                             xcat, K2t, Mp);
  chan_reduce<<<128, 256, 0, stream>>>(Mp, M);
  chan_apply<<<dim3(64, 8), 256, 0, stream>>>(V2t, M, x_up, x_skip, xcat);
  conv_mfma<<<dim3(32, 8), 512, 0, stream>>>(xcat, Wg, shb, out);
}